// Round 2
// baseline (552.265 us; speedup 1.0000x reference)
//
#include <hip/hip_runtime.h>
#include <cstdint>
#include <cstddef>

// Problem constants (fixed by setup_inputs)
#define Bn 16
#define Cn 3
#define Hn 768
#define Wn 768
#define Dn 64
#define HEn 192
#define WEn 192
#define Pn (HEn * WEn)   /* 36864 */
#define HWn (Hn * Wn)    /* 589824 */
#define TOPK 400
#define SENTK 0xFFFFFFFFu
#define PAD 16           /* pad accumulators to one 64B line each */
#define PXB 128          /* pixels per main block */

struct Ws {
  float ce_sum[Bn][PAD];        // 256 words
  int   ce_cnt[Bn][PAD];        // 256
  int   cnt1[2][Bn][PAD];       // 512
  int   cnt2[2][Bn][PAD];       // 512
  float mu2[2][Bn][Dn][PAD];    // 32768
  float mu1[2][Bn][Dn][PAD];    // 32768
  int   nsel[2][Bn];            // 32
  int   idxl[2][Bn][TOPK];      // 12800
  unsigned keys[2][Bn][Pn];     // 1179648
};
#define INIT_WORDS (256 + 256 + 512 + 512 + 32768 + 32768)
static_assert(offsetof(Ws, nsel) == (size_t)INIT_WORDS * 4, "ws layout");
static_assert(sizeof(Ws) < (size_t)6 * 1024 * 1024, "ws small");

__global__ void init_kernel(Ws* ws) {
  unsigned* w = (unsigned*)ws;
  int t = blockIdx.x * blockDim.x + threadIdx.x;
  for (int i = t; i < INIT_WORDS; i += gridDim.x * blockDim.x) w[i] = 0u;
}

__device__ __forceinline__ float wave_sum_f(float s) {
#pragma unroll
  for (int off = 32; off; off >>= 1) s += __shfl_down(s, off);
  return s;
}
__device__ __forceinline__ int wave_sum_i(int s) {
#pragma unroll
  for (int off = 32; off; off >>= 1) s += __shfl_down(s, off);
  return s;
}

// ---------------- CE loss ----------------
// grid (144, Bn), block 256; 4 float4 groups/thread; ONE atomic pair per block.
__global__ void ce_kernel(const float* __restrict__ out, const int* __restrict__ lab,
                          Ws* __restrict__ ws) {
  int b = blockIdx.y;
  const int NT = 144 * 256;  // threads per image
  int t = blockIdx.x * 256 + threadIdx.x;
  const float* base = out + (size_t)b * Cn * HWn;
  const int* lb_base = lab + (size_t)b * HWn;
  float s = 0.f; int c = 0;
#pragma unroll
  for (int it = 0; it < 4; it++) {
    int p4 = (t + it * NT) * 4;
    float4 a0 = *(const float4*)(base + p4);
    float4 a1 = *(const float4*)(base + HWn + p4);
    float4 a2 = *(const float4*)(base + 2 * HWn + p4);
    int4 lb = *(const int4*)(lb_base + p4);
    float x0s[4] = {a0.x, a0.y, a0.z, a0.w};
    float x1s[4] = {a1.x, a1.y, a1.z, a1.w};
    float x2s[4] = {a2.x, a2.y, a2.z, a2.w};
    int ls[4] = {lb.x, lb.y, lb.z, lb.w};
#pragma unroll
    for (int k = 0; k < 4; k++) {
      int l = ls[k];
      if (l != 255) {
        float x0 = x0s[k], x1 = x1s[k], x2 = x2s[k];
        float m = fmaxf(x0, fmaxf(x1, x2));
        float lse = m + __logf(__expf(x0 - m) + __expf(x1 - m) + __expf(x2 - m));
        float xl = (l == 0) ? x0 : ((l == 1) ? x1 : x2);
        s += lse - xl;
        c += 1;
      }
    }
  }
  s = wave_sum_f(s);
  c = wave_sum_i(c);
  __shared__ float ss[4];
  __shared__ int sc[4];
  int wid = threadIdx.x >> 6;
  if ((threadIdx.x & 63) == 0) { ss[wid] = s; sc[wid] = c; }
  __syncthreads();
  if (threadIdx.x == 0) {
    atomicAdd(&ws->ce_sum[b][0], ss[0] + ss[1] + ss[2] + ss[3]);
    atomicAdd(&ws->ce_cnt[b][0], sc[0] + sc[1] + sc[2] + sc[3]);
  }
}

// ---------------- main embedding pass ----------------
// grid (Pn/PXB, Bn, 2), block 256 = 4 waves; 128 pixels per block.
// Load phase (unchanged from the 100us R0 kernel): wave w owns channels
// [16w,16w+16), lane owns pixel pair (p0+2*lane,+1), 16 float2 loads.
// Finalize phase is now (a) DISTRIBUTED: wave w finalizes pixels
// [p0+32w, p0+32w+32), one per lane (4x parallelism vs the old wave0-only,
// half the serial gather depth), and (b) HOISTED: the 3 scattered o-loads and
// all conf/seg/mask math are issued BEFORE the embedding loads, so their
// ~900cyc gather latency overlaps the coalesced e-stream instead of sitting
// between the two barriers. Between barriers only: LDS sums -> key pack ->
// 2 coalesced stores.
__global__ void main_kernel(const float* __restrict__ o0, const float* __restrict__ o1,
                            const float* __restrict__ e0, const float* __restrict__ e1,
                            Ws* __restrict__ ws) {
  int arr = blockIdx.z;
  int b = blockIdx.y;
  int lane = threadIdx.x & 63, wv = threadIdx.x >> 6;
  int p0 = blockIdx.x * PXB;
  int pa = p0 + 2 * lane;

  const float* o = (arr ? o1 : o0) + (size_t)b * Cn * HWn;
  const float* e = (arr ? e1 : e0) + ((size_t)b * Dn + wv * 16) * Pn;

  // ---- phase 0a: issue scattered o-gathers for this wave's finalize pixel ----
  int pfin = p0 + 32 * wv + lane;  // valid for lane < 32
  float x0 = 0.f, x1 = 0.f, x2 = 0.f;
  if (lane < 32) {
    int i = pfin / WEn, j = pfin - i * WEn;
    int q = (4 * i) * Wn + 4 * j;
    x0 = o[q]; x1 = o[q + HWn]; x2 = o[q + 2 * HWn];
  }

  // ---- phase 0b: coalesced embedding loads (overlaps the gathers above) ----
  float va[16], vb[16];
  float sum0 = 0.f, sum1 = 0.f, sq0 = 0.f, sq1 = 0.f;
#pragma unroll
  for (int k = 0; k < 16; k++) {
    float2 x = *(const float2*)(e + (size_t)k * Pn + pa);
    va[k] = x.x; vb[k] = x.y;
    sum0 += x.x; sq0 += x.x * x.x;
    sum1 += x.y; sq1 += x.y * x.y;
  }

  // ---- phase 0c: finish mask math (no LDS dependence) ----
  bool m1 = false, m2 = false;
  if (lane < 32) {
    int sgc = 0; float m = x0;
    if (x1 > m) { m = x1; sgc = 1; }
    if (x2 > m) { m = x2; sgc = 2; }
    float conf = 1.0f / (__expf(x0 - m) + __expf(x1 - m) + __expf(x2 - m));
    m1 = (sgc == 1) && (conf > 0.8f);
    m2 = (sgc == 2) && (conf > 0.6f);
  }
  unsigned long long b1 = __ballot(m1), b2 = __ballot(m2);
  if (lane == 0) {
    int c1 = (int)__popcll(b1);
    int c2 = (int)__popcll(b2);
    if (c1) atomicAdd(&ws->cnt1[arr][b][0], c1);
    if (c2) atomicAdd(&ws->cnt2[arr][b][0], c2);
  }

  __shared__ float psum[4][PXB], psq[4][PXB];
  __shared__ float sscale[PXB];
  *(float2*)&psum[wv][2 * lane] = make_float2(sum0, sum1);
  *(float2*)&psq[wv][2 * lane] = make_float2(sq0, sq1);
  __syncthreads();

  // ---- phase 1: per-pixel totals -> key + scale (tiny critical section) ----
  if (lane < 32) {
    int px = 32 * wv + lane;
    float ts = psum[0][px] + psum[1][px] + psum[2][px] + psum[3][px];
    float tq = psq[0][px] + psq[1][px] + psq[2][px] + psq[3][px];
    unsigned kbv = SENTK;
    if (m1) {
      unsigned u = __float_as_uint(ts);  // sum is order-equivalent to mean (/64 exact)
      kbv = (u & 0x80000000u) ? ~u : (u | 0x80000000u);
      if (kbv == SENTK) kbv--;
    }
    ws->keys[arr][b][pfin] = kbv;        // 32 lanes x 4B contiguous per wave
    sscale[px] = m2 ? rsqrtf(tq) : 0.f;
  }
  __syncthreads();

  // ---- phase 2: rescale + per-channel butterfly + mu2 atomics ----
  float2 s2 = *(const float2*)&sscale[2 * lane];
  float rv = 0.f;
#pragma unroll
  for (int k = 0; k < 16; k++) {
    float x = va[k] * s2.x + vb[k] * s2.y;
#pragma unroll
    for (int off = 1; off < 64; off <<= 1) x += __shfl_xor(x, off);
    if (lane == k) rv = x;
  }
  if (lane < 16 && rv != 0.f)
    atomicAdd(&ws->mu2[arr][b][wv * 16 + lane][0], rv);
}

// ---------------- radix select top-400 smallest keys ----------------
// grid 32 (arr*16+b), block 1024. 11-bit digits x 3 levels (shifts 21/10/0),
// 2048-bin LDS histogram, exact uint4 key loads (9 iters per scan).
__global__ void __launch_bounds__(1024) select_kernel(Ws* __restrict__ ws) {
  int arr = blockIdx.x >> 4;
  int b = blockIdx.x & 15;
  int tid = threadIdx.x;
  const uint4* __restrict__ keys4 = (const uint4*)ws->keys[arr][b];
  int c1 = ws->cnt1[arr][b][0];
  if (c1 <= TOPK) {
    if (tid == 0) ws->nsel[arr][b] = 0;
    return;
  }
  __shared__ int hist[2048];
  __shared__ int super[128];
  __shared__ int tieBuf[256];
  __shared__ unsigned sPrefix;
  __shared__ int sKRem, nBelow, nTie;
  if (tid == 0) { sPrefix = 0u; sKRem = TOPK; }

  const int shifts[3] = {21, 10, 0};
  const unsigned bmask[3] = {2047u, 2047u, 1023u};
  const int nbins[3] = {2048, 2048, 1024};

  for (int lvl = 0; lvl < 3; lvl++) {
    hist[tid] = 0;
    hist[tid + 1024] = 0;
    __syncthreads();
    unsigned pref = sPrefix;
    int shift = shifts[lvl];
    unsigned bm = bmask[lvl];
#pragma unroll
    for (int it = 0; it < 9; it++) {
      uint4 u4 = keys4[it * 1024 + tid];
      unsigned us[4] = {u4.x, u4.y, u4.z, u4.w};
#pragma unroll
      for (int k = 0; k < 4; k++) {
        unsigned u = us[k];
        if (u == SENTK) continue;
        if (lvl == 1 && (u >> 21) != (pref >> 21)) continue;
        if (lvl == 2 && (u >> 10) != (pref >> 10)) continue;
        atomicAdd(&hist[(u >> shift) & bm], 1);
      }
    }
    __syncthreads();
    int SB = nbins[lvl] >> 7;  // 16 or 8
    if (tid < 128) {
      int s = 0;
      for (int k = 0; k < SB; k++) s += hist[tid * SB + k];
      super[tid] = s;
    }
    __syncthreads();
    if (tid == 0) {
      int k = sKRem, cum = 0, sb = 127;
      for (int t = 0; t < 128; t++) {
        if (cum + super[t] >= k) { sb = t; break; }
        cum += super[t];
      }
      int j = sb * SB + SB - 1;
      for (int t = sb * SB; t < sb * SB + SB; t++) {
        if (cum + hist[t] >= k) { j = t; k -= cum; break; }
        cum += hist[t];
      }
      sKRem = k;
      sPrefix = pref | ((unsigned)j << shift);
    }
    __syncthreads();
  }
  unsigned T = sPrefix;
  int kRem = sKRem;
  if (tid == 0) { nBelow = 0; nTie = 0; }
  __syncthreads();
  int* idxl = ws->idxl[arr][b];
#pragma unroll
  for (int it = 0; it < 9; it++) {
    uint4 u4 = keys4[it * 1024 + tid];
    unsigned us[4] = {u4.x, u4.y, u4.z, u4.w};
#pragma unroll
    for (int k = 0; k < 4; k++) {
      unsigned u = us[k];
      int p = (it * 1024 + tid) * 4 + k;
      if (u < T) {
        int pos = atomicAdd(&nBelow, 1);
        if (pos < TOPK) idxl[pos] = p;
      } else if (u == T) {
        int tp = atomicAdd(&nTie, 1);
        if (tp < 256) tieBuf[tp] = p;
      }
    }
  }
  __syncthreads();
  if (tid == 0) {
    int nb = nBelow;
    int tn = nTie < 256 ? nTie : 256;
    int take = kRem < tn ? kRem : tn;
    // stable tie-break: smallest pixel indices first (matches stable argsort)
    for (int r = 0; r < take; r++) {
      int mi = r;
      for (int t = r + 1; t < tn; t++)
        if (tieBuf[t] < tieBuf[mi]) mi = t;
      int tmp = tieBuf[r]; tieBuf[r] = tieBuf[mi]; tieBuf[mi] = tmp;
      if (nb + r < TOPK) idxl[nb + r] = tieBuf[r];
    }
    int ns = nb + take;
    ws->nsel[arr][b] = ns > TOPK ? TOPK : ns;
  }
}

// ---------------- class-1 accumulation over selected 400 ----------------
// grid (7, 32), block 256 = 4 waves x 16 channels, 64 pixels per block chunk.
__global__ void accum1_kernel(const float* __restrict__ e0, const float* __restrict__ e1,
                              Ws* __restrict__ ws) {
  int arr = blockIdx.y >> 4;
  int b = blockIdx.y & 15;
  int chunk = blockIdx.x;
  int ns = ws->nsel[arr][b];
  if (chunk * 64 >= ns) return;  // block-uniform early exit
  int lane = threadIdx.x & 63, wv = threadIdx.x >> 6;
  int t = chunk * 64 + lane;
  bool valid = t < ns;
  int p = valid ? ws->idxl[arr][b][t] : 0;
  const float* e = (arr ? e1 : e0) + ((size_t)b * Dn + wv * 16) * Pn;
  float v[16]; float sq = 0.f;
#pragma unroll
  for (int k = 0; k < 16; k++) {
    float x = e[(size_t)k * Pn + p];
    v[k] = x; sq += x * x;
  }
  __shared__ float psq[4][64];
  psq[wv][lane] = sq;
  __syncthreads();
  float tq = psq[0][lane] + psq[1][lane] + psq[2][lane] + psq[3][lane];
  float s = valid ? rsqrtf(tq) : 0.f;
  float rv = 0.f;
#pragma unroll
  for (int k = 0; k < 16; k++) {
    float x = v[k] * s;
#pragma unroll
    for (int off = 1; off < 64; off <<= 1) x += __shfl_xor(x, off);
    if (lane == k) rv = x;
  }
  if (lane < 16 && rv != 0.f)
    atomicAdd(&ws->mu1[arr][b][wv * 16 + lane][0], rv);
}

// ---------------- final combine ----------------
__global__ void final_kernel(Ws* __restrict__ ws, float* __restrict__ out) {
  int t = threadIdx.x;
  float ce = 0.f, num = 0.f;
  int cnt = 0;
  if (t < Bn) {
    int cc = ws->ce_cnt[t][0];
    ce = ws->ce_sum[t][0] / (float)(cc > 1 ? cc : 1);
    int c1o = ws->cnt1[0][t][0], c1a = ws->cnt1[1][t][0];
    if (c1o > TOPK && c1a > TOPK) {
      float dot = 0.f;
      for (int d = 0; d < Dn; d++) dot += ws->mu1[0][t][d][0] * ws->mu1[1][t][d][0];
      num += 1.f - dot / ((float)TOPK * (float)TOPK);
      cnt += 1;
    }
    int c2o = ws->cnt2[0][t][0], c2a = ws->cnt2[1][t][0];
    if (c2o > 0 && c2a > 0) {
      float dot = 0.f;
      for (int d = 0; d < Dn; d++) dot += ws->mu2[0][t][d][0] * ws->mu2[1][t][d][0];
      float den = (float)(c2o > 1 ? c2o : 1) * (float)(c2a > 1 ? c2a : 1);
      num += 1.f - dot / den;
      cnt += 1;
    }
  }
#pragma unroll
  for (int off = 32; off; off >>= 1) {
    ce += __shfl_down(ce, off);
    num += __shfl_down(num, off);
    cnt += __shfl_down(cnt, off);
  }
  if (t == 0) {
    float loss_ce = ce / (float)Bn;
    float lm = num / (float)(cnt > 1 ? cnt : 1);
    out[0] = loss_ce + 2.f * lm;
    out[1] = loss_ce;
    out[2] = lm;
  }
}

extern "C" void kernel_launch(void* const* d_in, const int* in_sizes, int n_in,
                              void* d_out, int out_size, void* d_ws, size_t ws_size,
                              hipStream_t stream) {
  const float* outputs      = (const float*)d_in[0];
  const float* embeddings   = (const float*)d_in[1];
  const int*   class_labels = (const int*)d_in[2];
  const float* outputs_aug  = (const float*)d_in[3];
  const float* emb_aug      = (const float*)d_in[4];
  // d_in[5] (class_labels_aug) is unused by the reference loss.
  Ws* ws = (Ws*)d_ws;
  float* out = (float*)d_out;

  init_kernel<<<32, 256, 0, stream>>>(ws);
  ce_kernel<<<dim3(144, Bn), 256, 0, stream>>>(outputs, class_labels, ws);
  main_kernel<<<dim3(Pn / PXB, Bn, 2), 256, 0, stream>>>(outputs, outputs_aug,
                                                         embeddings, emb_aug, ws);
  select_kernel<<<32, 1024, 0, stream>>>(ws);
  accum1_kernel<<<dim3(7, 32), 256, 0, stream>>>(embeddings, emb_aug, ws);
  final_kernel<<<1, 64, 0, stream>>>(ws, out);
}

// Round 3
// 526.036 us; speedup vs baseline: 1.0499x; 1.0499x over previous
//
#include <hip/hip_runtime.h>
#include <cstdint>
#include <cstddef>

// Problem constants (fixed by setup_inputs)
#define Bn 16
#define Cn 3
#define Hn 768
#define Wn 768
#define Dn 64
#define HEn 192
#define WEn 192
#define Pn (HEn * WEn)   /* 36864 */
#define HWn (Hn * Wn)    /* 589824 */
#define TOPK 400
#define SENTK 0xFFFFFFFFu
#define PAD 16           /* pad accumulators to one 64B line each */
#define PXB 128          /* pixels per chunk */
#define CHUNKS 4         /* chunks per block: amortize butterfly+atomics */

struct Ws {
  float ce_sum[Bn][PAD];        // 256 words
  int   ce_cnt[Bn][PAD];        // 256
  int   cnt1[2][Bn][PAD];       // 512
  int   cnt2[2][Bn][PAD];       // 512
  float mu2[2][Bn][Dn][PAD];    // 32768
  float mu1[2][Bn][Dn][PAD];    // 32768
  int   nsel[2][Bn];            // 32
  int   idxl[2][Bn][TOPK];      // 12800
  unsigned keys[2][Bn][Pn];     // 1179648
};
#define INIT_WORDS (256 + 256 + 512 + 512 + 32768 + 32768)
static_assert(offsetof(Ws, nsel) == (size_t)INIT_WORDS * 4, "ws layout");
static_assert(sizeof(Ws) < (size_t)6 * 1024 * 1024, "ws small");

__global__ void init_kernel(Ws* ws) {
  unsigned* w = (unsigned*)ws;
  int t = blockIdx.x * blockDim.x + threadIdx.x;
  for (int i = t; i < INIT_WORDS; i += gridDim.x * blockDim.x) w[i] = 0u;
}

__device__ __forceinline__ float wave_sum_f(float s) {
#pragma unroll
  for (int off = 32; off; off >>= 1) s += __shfl_down(s, off);
  return s;
}
__device__ __forceinline__ int wave_sum_i(int s) {
#pragma unroll
  for (int off = 32; off; off >>= 1) s += __shfl_down(s, off);
  return s;
}

// ---------------- CE loss ----------------
// grid (144, Bn), block 256; 4 float4 groups/thread; ONE atomic pair per block.
__global__ void ce_kernel(const float* __restrict__ out, const int* __restrict__ lab,
                          Ws* __restrict__ ws) {
  int b = blockIdx.y;
  const int NT = 144 * 256;  // threads per image
  int t = blockIdx.x * 256 + threadIdx.x;
  const float* base = out + (size_t)b * Cn * HWn;
  const int* lb_base = lab + (size_t)b * HWn;
  float s = 0.f; int c = 0;
#pragma unroll
  for (int it = 0; it < 4; it++) {
    int p4 = (t + it * NT) * 4;
    float4 a0 = *(const float4*)(base + p4);
    float4 a1 = *(const float4*)(base + HWn + p4);
    float4 a2 = *(const float4*)(base + 2 * HWn + p4);
    int4 lb = *(const int4*)(lb_base + p4);
    float x0s[4] = {a0.x, a0.y, a0.z, a0.w};
    float x1s[4] = {a1.x, a1.y, a1.z, a1.w};
    float x2s[4] = {a2.x, a2.y, a2.z, a2.w};
    int ls[4] = {lb.x, lb.y, lb.z, lb.w};
#pragma unroll
    for (int k = 0; k < 4; k++) {
      int l = ls[k];
      if (l != 255) {
        float x0 = x0s[k], x1 = x1s[k], x2 = x2s[k];
        float m = fmaxf(x0, fmaxf(x1, x2));
        float lse = m + __logf(__expf(x0 - m) + __expf(x1 - m) + __expf(x2 - m));
        float xl = (l == 0) ? x0 : ((l == 1) ? x1 : x2);
        s += lse - xl;
        c += 1;
      }
    }
  }
  s = wave_sum_f(s);
  c = wave_sum_i(c);
  __shared__ float ss[4];
  __shared__ int sc[4];
  int wid = threadIdx.x >> 6;
  if ((threadIdx.x & 63) == 0) { ss[wid] = s; sc[wid] = c; }
  __syncthreads();
  if (threadIdx.x == 0) {
    atomicAdd(&ws->ce_sum[b][0], ss[0] + ss[1] + ss[2] + ss[3]);
    atomicAdd(&ws->ce_cnt[b][0], sc[0] + sc[1] + sc[2] + sc[3]);
  }
}

// ---------------- main embedding pass ----------------
// grid (Pn/(PXB*CHUNKS), Bn, 2) = (72,16,2), block 256 = 4 waves.
// Per-chunk schedule is IDENTICAL to the proven 100us R0 kernel (16 float2
// coalesced loads; wave0-only finalize between the two barriers). Two
// amortizations on top:
//  (1) CHUNKS=4 per block: phase-2 becomes a per-lane register FMA per chunk;
//      the 16x6 shuffle butterfly + mu2/cnt atomics run ONCE per block (4x less).
//  (2) wave0 software-pipelines its 6 scattered o-gathers: chunk c+1's values
//      are prefetched during chunk c's critical section and consumed only
//      after chunk c+1's e-load phase -> gather latency leaves the
//      inter-barrier critical path.
__global__ void __launch_bounds__(256, 6)
main_kernel(const float* __restrict__ o0, const float* __restrict__ o1,
            const float* __restrict__ e0, const float* __restrict__ e1,
            Ws* __restrict__ ws) {
  int arr = blockIdx.z;
  int b = blockIdx.y;
  int lane = threadIdx.x & 63, wv = threadIdx.x >> 6;
  int base_p = blockIdx.x * (PXB * CHUNKS);

  const float* o = (arr ? o1 : o0) + (size_t)b * Cn * HWn;
  const float* e = (arr ? e1 : e0) + ((size_t)b * Dn + wv * 16) * Pn;

  __shared__ float psum[4][PXB], psq[4][PXB];
  __shared__ float sscale[PXB];

  float acc[16];
#pragma unroll
  for (int k = 0; k < 16; k++) acc[k] = 0.f;
  int c1a = 0, c2a = 0;

  // prefetch chunk 0 gathers (wave0 only); overlaps the first e-load burst
  float px0[2], px1[2], px2[2];
  if (wv == 0) {
#pragma unroll
    for (int h = 0; h < 2; h++) {
      int p = base_p + 2 * lane + h;
      int i = p / WEn, j = p - i * WEn;
      int q = (4 * i) * Wn + 4 * j;
      px0[h] = o[q]; px1[h] = o[q + HWn]; px2[h] = o[q + 2 * HWn];
    }
  }

#pragma unroll 1
  for (int c = 0; c < CHUNKS; c++) {
    int p0 = base_p + c * PXB;
    int pa = p0 + 2 * lane;

    float va[16], vb[16];
    float sum0 = 0.f, sum1 = 0.f, sq0 = 0.f, sq1 = 0.f;
#pragma unroll
    for (int k = 0; k < 16; k++) {
      float2 x = *(const float2*)(e + (size_t)k * Pn + pa);
      va[k] = x.x; vb[k] = x.y;
      sum0 += x.x; sq0 += x.x * x.x;
      sum1 += x.y; sq1 += x.y * x.y;
    }
    *(float2*)&psum[wv][2 * lane] = make_float2(sum0, sum1);
    *(float2*)&psq[wv][2 * lane] = make_float2(sq0, sq1);
    __syncthreads();

    if (wv == 0) {
      unsigned kb[2]; float sc[2]; bool m1f[2], m2f[2];
#pragma unroll
      for (int h = 0; h < 2; h++) {
        int px = 2 * lane + h;
        float ts = psum[0][px] + psum[1][px] + psum[2][px] + psum[3][px];
        float tq = psq[0][px] + psq[1][px] + psq[2][px] + psq[3][px];
        float x0 = px0[h], x1 = px1[h], x2 = px2[h];
        int sgc = 0; float m = x0;
        if (x1 > m) { m = x1; sgc = 1; }
        if (x2 > m) { m = x2; sgc = 2; }
        float conf = 1.0f / (__expf(x0 - m) + __expf(x1 - m) + __expf(x2 - m));
        bool m1 = (sgc == 1) && (conf > 0.8f);
        bool m2 = (sgc == 2) && (conf > 0.6f);
        unsigned kbv = SENTK;
        if (m1) {
          unsigned u = __float_as_uint(ts);
          kbv = (u & 0x80000000u) ? ~u : (u | 0x80000000u);
          if (kbv == SENTK) kbv--;
        }
        kb[h] = kbv;
        sc[h] = m2 ? rsqrtf(tq) : 0.f;
        m1f[h] = m1; m2f[h] = m2;
      }
      *(uint2*)&ws->keys[arr][b][pa] = make_uint2(kb[0], kb[1]);
      *(float2*)&sscale[2 * lane] = make_float2(sc[0], sc[1]);
      unsigned long long b10 = __ballot(m1f[0]), b11 = __ballot(m1f[1]);
      unsigned long long b20 = __ballot(m2f[0]), b21 = __ballot(m2f[1]);
      c1a += (int)__popcll(b10) + (int)__popcll(b11);
      c2a += (int)__popcll(b20) + (int)__popcll(b21);
      // prefetch next chunk's gathers; consumed after next e-load phase
      if (c + 1 < CHUNKS) {
#pragma unroll
        for (int h = 0; h < 2; h++) {
          int p = p0 + PXB + 2 * lane + h;
          int i = p / WEn, j = p - i * WEn;
          int q = (4 * i) * Wn + 4 * j;
          px0[h] = o[q]; px1[h] = o[q + HWn]; px2[h] = o[q + 2 * HWn];
        }
      }
    }
    __syncthreads();

    float2 s2 = *(const float2*)&sscale[2 * lane];
#pragma unroll
    for (int k = 0; k < 16; k++)
      acc[k] += va[k] * s2.x + vb[k] * s2.y;
  }

  // once per block: per-channel butterfly + atomics
  float rv = 0.f;
#pragma unroll
  for (int k = 0; k < 16; k++) {
    float x = acc[k];
#pragma unroll
    for (int off = 1; off < 64; off <<= 1) x += __shfl_xor(x, off);
    if (lane == k) rv = x;
  }
  if (lane < 16 && rv != 0.f)
    atomicAdd(&ws->mu2[arr][b][wv * 16 + lane][0], rv);
  if (wv == 0 && lane == 0) {
    if (c1a) atomicAdd(&ws->cnt1[arr][b][0], c1a);
    if (c2a) atomicAdd(&ws->cnt2[arr][b][0], c2a);
  }
}

// ---------------- radix select top-400 smallest keys ----------------
// grid 32 (arr*16+b), block 1024. 11-bit digits x 3 levels (shifts 21/10/0),
// 2048-bin LDS histogram, exact uint4 key loads (9 iters per scan).
__global__ void __launch_bounds__(1024) select_kernel(Ws* __restrict__ ws) {
  int arr = blockIdx.x >> 4;
  int b = blockIdx.x & 15;
  int tid = threadIdx.x;
  const uint4* __restrict__ keys4 = (const uint4*)ws->keys[arr][b];
  int c1 = ws->cnt1[arr][b][0];
  if (c1 <= TOPK) {
    if (tid == 0) ws->nsel[arr][b] = 0;
    return;
  }
  __shared__ int hist[2048];
  __shared__ int super[128];
  __shared__ int tieBuf[256];
  __shared__ unsigned sPrefix;
  __shared__ int sKRem, nBelow, nTie;
  if (tid == 0) { sPrefix = 0u; sKRem = TOPK; }

  const int shifts[3] = {21, 10, 0};
  const unsigned bmask[3] = {2047u, 2047u, 1023u};
  const int nbins[3] = {2048, 2048, 1024};

  for (int lvl = 0; lvl < 3; lvl++) {
    hist[tid] = 0;
    hist[tid + 1024] = 0;
    __syncthreads();
    unsigned pref = sPrefix;
    int shift = shifts[lvl];
    unsigned bm = bmask[lvl];
#pragma unroll
    for (int it = 0; it < 9; it++) {
      uint4 u4 = keys4[it * 1024 + tid];
      unsigned us[4] = {u4.x, u4.y, u4.z, u4.w};
#pragma unroll
      for (int k = 0; k < 4; k++) {
        unsigned u = us[k];
        if (u == SENTK) continue;
        if (lvl == 1 && (u >> 21) != (pref >> 21)) continue;
        if (lvl == 2 && (u >> 10) != (pref >> 10)) continue;
        atomicAdd(&hist[(u >> shift) & bm], 1);
      }
    }
    __syncthreads();
    int SB = nbins[lvl] >> 7;  // 16 or 8
    if (tid < 128) {
      int s = 0;
      for (int k = 0; k < SB; k++) s += hist[tid * SB + k];
      super[tid] = s;
    }
    __syncthreads();
    if (tid == 0) {
      int k = sKRem, cum = 0, sb = 127;
      for (int t = 0; t < 128; t++) {
        if (cum + super[t] >= k) { sb = t; break; }
        cum += super[t];
      }
      int j = sb * SB + SB - 1;
      for (int t = sb * SB; t < sb * SB + SB; t++) {
        if (cum + hist[t] >= k) { j = t; k -= cum; break; }
        cum += hist[t];
      }
      sKRem = k;
      sPrefix = pref | ((unsigned)j << shift);
    }
    __syncthreads();
  }
  unsigned T = sPrefix;
  int kRem = sKRem;
  if (tid == 0) { nBelow = 0; nTie = 0; }
  __syncthreads();
  int* idxl = ws->idxl[arr][b];
#pragma unroll
  for (int it = 0; it < 9; it++) {
    uint4 u4 = keys4[it * 1024 + tid];
    unsigned us[4] = {u4.x, u4.y, u4.z, u4.w};
#pragma unroll
    for (int k = 0; k < 4; k++) {
      unsigned u = us[k];
      int p = (it * 1024 + tid) * 4 + k;
      if (u < T) {
        int pos = atomicAdd(&nBelow, 1);
        if (pos < TOPK) idxl[pos] = p;
      } else if (u == T) {
        int tp = atomicAdd(&nTie, 1);
        if (tp < 256) tieBuf[tp] = p;
      }
    }
  }
  __syncthreads();
  if (tid == 0) {
    int nb = nBelow;
    int tn = nTie < 256 ? nTie : 256;
    int take = kRem < tn ? kRem : tn;
    // stable tie-break: smallest pixel indices first (matches stable argsort)
    for (int r = 0; r < take; r++) {
      int mi = r;
      for (int t = r + 1; t < tn; t++)
        if (tieBuf[t] < tieBuf[mi]) mi = t;
      int tmp = tieBuf[r]; tieBuf[r] = tieBuf[mi]; tieBuf[mi] = tmp;
      if (nb + r < TOPK) idxl[nb + r] = tieBuf[r];
    }
    int ns = nb + take;
    ws->nsel[arr][b] = ns > TOPK ? TOPK : ns;
  }
}

// ---------------- class-1 accumulation over selected 400 ----------------
// grid (7, 32), block 256 = 4 waves x 16 channels, 64 pixels per block chunk.
__global__ void accum1_kernel(const float* __restrict__ e0, const float* __restrict__ e1,
                              Ws* __restrict__ ws) {
  int arr = blockIdx.y >> 4;
  int b = blockIdx.y & 15;
  int chunk = blockIdx.x;
  int ns = ws->nsel[arr][b];
  if (chunk * 64 >= ns) return;  // block-uniform early exit
  int lane = threadIdx.x & 63, wv = threadIdx.x >> 6;
  int t = chunk * 64 + lane;
  bool valid = t < ns;
  int p = valid ? ws->idxl[arr][b][t] : 0;
  const float* e = (arr ? e1 : e0) + ((size_t)b * Dn + wv * 16) * Pn;
  float v[16]; float sq = 0.f;
#pragma unroll
  for (int k = 0; k < 16; k++) {
    float x = e[(size_t)k * Pn + p];
    v[k] = x; sq += x * x;
  }
  __shared__ float psq[4][64];
  psq[wv][lane] = sq;
  __syncthreads();
  float tq = psq[0][lane] + psq[1][lane] + psq[2][lane] + psq[3][lane];
  float s = valid ? rsqrtf(tq) : 0.f;
  float rv = 0.f;
#pragma unroll
  for (int k = 0; k < 16; k++) {
    float x = v[k] * s;
#pragma unroll
    for (int off = 1; off < 64; off <<= 1) x += __shfl_xor(x, off);
    if (lane == k) rv = x;
  }
  if (lane < 16 && rv != 0.f)
    atomicAdd(&ws->mu1[arr][b][wv * 16 + lane][0], rv);
}

// ---------------- final combine ----------------
__global__ void final_kernel(Ws* __restrict__ ws, float* __restrict__ out) {
  int t = threadIdx.x;
  float ce = 0.f, num = 0.f;
  int cnt = 0;
  if (t < Bn) {
    int cc = ws->ce_cnt[t][0];
    ce = ws->ce_sum[t][0] / (float)(cc > 1 ? cc : 1);
    int c1o = ws->cnt1[0][t][0], c1a = ws->cnt1[1][t][0];
    if (c1o > TOPK && c1a > TOPK) {
      float dot = 0.f;
      for (int d = 0; d < Dn; d++) dot += ws->mu1[0][t][d][0] * ws->mu1[1][t][d][0];
      num += 1.f - dot / ((float)TOPK * (float)TOPK);
      cnt += 1;
    }
    int c2o = ws->cnt2[0][t][0], c2a = ws->cnt2[1][t][0];
    if (c2o > 0 && c2a > 0) {
      float dot = 0.f;
      for (int d = 0; d < Dn; d++) dot += ws->mu2[0][t][d][0] * ws->mu2[1][t][d][0];
      float den = (float)(c2o > 1 ? c2o : 1) * (float)(c2a > 1 ? c2a : 1);
      num += 1.f - dot / den;
      cnt += 1;
    }
  }
#pragma unroll
  for (int off = 32; off; off >>= 1) {
    ce += __shfl_down(ce, off);
    num += __shfl_down(num, off);
    cnt += __shfl_down(cnt, off);
  }
  if (t == 0) {
    float loss_ce = ce / (float)Bn;
    float lm = num / (float)(cnt > 1 ? cnt : 1);
    out[0] = loss_ce + 2.f * lm;
    out[1] = loss_ce;
    out[2] = lm;
  }
}

extern "C" void kernel_launch(void* const* d_in, const int* in_sizes, int n_in,
                              void* d_out, int out_size, void* d_ws, size_t ws_size,
                              hipStream_t stream) {
  const float* outputs      = (const float*)d_in[0];
  const float* embeddings   = (const float*)d_in[1];
  const int*   class_labels = (const int*)d_in[2];
  const float* outputs_aug  = (const float*)d_in[3];
  const float* emb_aug      = (const float*)d_in[4];
  // d_in[5] (class_labels_aug) is unused by the reference loss.
  Ws* ws = (Ws*)d_ws;
  float* out = (float*)d_out;

  init_kernel<<<32, 256, 0, stream>>>(ws);
  ce_kernel<<<dim3(144, Bn), 256, 0, stream>>>(outputs, class_labels, ws);
  main_kernel<<<dim3(Pn / (PXB * CHUNKS), Bn, 2), 256, 0, stream>>>(
      outputs, outputs_aug, embeddings, emb_aug, ws);
  select_kernel<<<32, 1024, 0, stream>>>(ws);
  accum1_kernel<<<dim3(7, 32), 256, 0, stream>>>(embeddings, emb_aug, ws);
  final_kernel<<<1, 64, 0, stream>>>(ws, out);
}